// Round 3
// baseline (278.688 us; speedup 1.0000x reference)
//
#include <hip/hip_runtime.h>
#include <stdint.h>

// Binary conv 3x3, stride 1, pad 1:
//   x: (32, 256, 56, 56) fp32 NCHW  -> binarize sign
//   w: (256, 256, 3, 3)  fp32 OIHW  -> binarize sign
//   out[n,o,h,w] = sum_{valid taps, c} xb * wb
// XNOR-popcount formulation: pack sign bits along C (256 -> 8 u32).
// Per valid tap: contribution = 256 - 2*popc(xbits ^ wbits).
// out = 256*nvalid - 2*sum_popc.

#define N_BATCH 32
#define C_IN    256
#define HH      56
#define WW_     56
#define HW      (HH * WW_)   // 3136
#define C_OUT   256
#define WORDS   8            // 256 / 32
#define TAPS    9
#define OBLK    8            // output channels per thread

// ---- pass 1: binarize + bitpack x -> xp[n][s][word], word over c ----
__global__ __launch_bounds__(256) void pack_x_kernel(const float* __restrict__ x,
                                                     uint32_t* __restrict__ xp) {
    int tid = blockIdx.x * 256 + threadIdx.x;       // 32*3136*8 = 802816 total
    int s = tid % HW;
    int t = tid / HW;
    int n = t % N_BATCH;
    int word = t / N_BATCH;                          // 0..7
    const float* px = x + ((size_t)(n * C_IN + word * 32)) * HW + s;
    uint32_t bits = 0;
#pragma unroll
    for (int i = 0; i < 32; ++i) {
        float v = px[(size_t)i * HW];                // coalesced across lanes (s contiguous)
        bits |= (v > 0.0f ? 1u : 0u) << i;
    }
    xp[((size_t)(n * HW + s)) * WORDS + word] = bits;
}

// ---- pass 2: binarize + bitpack w -> wp[o][tap][word] ----
__global__ __launch_bounds__(256) void pack_w_kernel(const float* __restrict__ w,
                                                     uint32_t* __restrict__ wp) {
    int tid = blockIdx.x * 256 + threadIdx.x;        // 256*9*8 = 18432 total
    int o = tid / (TAPS * WORDS);
    int r = tid % (TAPS * WORDS);
    int tap = r / WORDS;
    int j = r % WORDS;
    uint32_t bits = 0;
#pragma unroll
    for (int i = 0; i < 32; ++i) {
        int c = j * 32 + i;
        float v = w[((size_t)(o * C_IN + c)) * TAPS + tap];
        bits |= (v > 0.0f ? 1u : 0u) << i;
    }
    wp[tid] = bits;                                  // layout [o][tap][j]
}

// ---- pass 3: xnor-popcount conv ----
__global__ __launch_bounds__(256) void bconv_kernel(const uint32_t* __restrict__ xp,
                                                    const uint32_t* __restrict__ wp,
                                                    float* __restrict__ out) {
    int s = blockIdx.x * 256 + threadIdx.x;
    if (s >= HW) return;
    int n = blockIdx.z;
    int o_base = blockIdx.y * OBLK;
    int h = s / WW_;
    int w = s % WW_;

    int acc[OBLK];
#pragma unroll
    for (int o = 0; o < OBLK; ++o) acc[o] = 0;
    int nvalid = 0;

    const uint32_t* xpn = xp + (size_t)n * HW * WORDS;

#pragma unroll
    for (int kh = -1; kh <= 1; ++kh) {
        int hh = h + kh;
        if (hh < 0 || hh >= HH) continue;
#pragma unroll
        for (int kw = -1; kw <= 1; ++kw) {
            int ww = w + kw;
            if (ww < 0 || ww >= WW_) continue;
            ++nvalid;
            const uint32_t* px = xpn + (size_t)(hh * WW_ + ww) * WORDS;
            uint4 a = *reinterpret_cast<const uint4*>(px);
            uint4 b = *reinterpret_cast<const uint4*>(px + 4);
            uint32_t xw[8] = {a.x, a.y, a.z, a.w, b.x, b.y, b.z, b.w};
            int tap = (kh + 1) * 3 + (kw + 1);
#pragma unroll
            for (int o = 0; o < OBLK; ++o) {
                // uniform index (blockIdx.y + constants) -> scalar loads, SGPR-held
                const uint32_t* pw = wp + ((size_t)(o_base + o) * TAPS + tap) * WORDS;
#pragma unroll
                for (int j = 0; j < WORDS; ++j) {
                    acc[o] += __popc(xw[j] ^ pw[j]);   // v_xor + v_bcnt (bcnt fuses add)
                }
            }
        }
    }

#pragma unroll
    for (int o = 0; o < OBLK; ++o) {
        out[((size_t)(n * C_OUT + o_base + o)) * HW + s] =
            (float)(C_IN * nvalid - 2 * acc[o]);
    }
}

extern "C" void kernel_launch(void* const* d_in, const int* in_sizes, int n_in,
                              void* d_out, int out_size, void* d_ws, size_t ws_size,
                              hipStream_t stream) {
    const float* x = (const float*)d_in[0];
    const float* w = (const float*)d_in[1];
    float* out = (float*)d_out;

    uint32_t* xp = (uint32_t*)d_ws;                               // 802816 u32 = 3.21 MB
    uint32_t* wp = xp + (size_t)N_BATCH * HW * WORDS;             //  73728 u32 = 288 KB

    pack_x_kernel<<<dim3(HW * N_BATCH * WORDS / 256), 256, 0, stream>>>(x, xp);
    pack_w_kernel<<<dim3(C_OUT * TAPS * WORDS / 256), 256, 0, stream>>>(w, wp);

    dim3 grid((HW + 255) / 256, C_OUT / OBLK, N_BATCH);
    bconv_kernel<<<grid, 256, 0, stream>>>(xp, wp, out);
}